// Round 5
// baseline (176.752 us; speedup 1.0000x reference)
//
#include <hip/hip_runtime.h>
#include <stdint.h>

#define L2E 1.44269504088896340736f

typedef _Float16 half8 __attribute__((ext_vector_type(8)));
typedef float floatx4 __attribute__((ext_vector_type(4)));
typedef float floatx16 __attribute__((ext_vector_type(16)));

static __device__ __forceinline__ unsigned short f32_to_f16u(float f) {
  union { _Float16 h; unsigned short s; } cv; cv.h = (_Float16)f; return cv.s;
}
static __device__ __forceinline__ _Float16 f32h(float f) { return (_Float16)f; }

// ---------------------------------------------------------------------------
// Projection GEMM. z=0: q,k (64 cols) from depth -> qT,kT [b][n][32] fp16.
// z=1: ALL 256 v cols from rgb -> v [b][co][n] fp16 (Wv staged per-32c slice,
// A-gather done ONCE per block, prefetched across the k-loop).
// ---------------------------------------------------------------------------
__global__ __launch_bounds__(256, 2) void proj_kernel(
    const float* __restrict__ rgb,
    const float* __restrict__ depth,
    const float* __restrict__ Wq, const float* __restrict__ bq,
    const float* __restrict__ Wk, const float* __restrict__ bk,
    const float* __restrict__ Wv, const float* __restrict__ bv,
    unsigned short* __restrict__ qT,
    unsigned short* __restrict__ kT,
    unsigned short* __restrict__ v)
{
  __shared__ __align__(16) unsigned short sW[64 * 256];  // 32 KB

  const int n0 = blockIdx.x * 64;
  const int b  = blockIdx.y;
  const int z  = blockIdx.z;
  const int t  = threadIdx.x;
  const int w  = t >> 6;
  const int lane = t & 63;
  const int l15 = lane & 15;
  const int q4  = lane >> 4;
  const int n_row = n0 + 16 * w + l15;

  if (z == 0) {
    const float* xb = depth + (size_t)b * 256 * 4096;
    // stage W(q,k) [64 o][256 c] fp16, swizzled by (og&7)
#pragma unroll
    for (int it = 0; it < 8; it++) {
      int L = it * 256 + t;
      int og = L >> 5;
      int phys = L & 31;
      int ci = phys ^ (og & 7);
      const float* wr = (og < 32) ? (Wq + (size_t)og * 256) : (Wk + (size_t)(og - 32) * 256);
      float4 w0 = *(const float4*)(wr + ci * 8);
      float4 w1 = *(const float4*)(wr + ci * 8 + 4);
      half8 h;
      h[0] = f32h(w0.x); h[1] = f32h(w0.y); h[2] = f32h(w0.z); h[3] = f32h(w0.w);
      h[4] = f32h(w1.x); h[5] = f32h(w1.y); h[6] = f32h(w1.z); h[7] = f32h(w1.w);
      *(half8*)&sW[(size_t)L * 8] = h;
    }
    float bias[4];
#pragma unroll
    for (int ct = 0; ct < 4; ct++) {
      int og = ct * 16 + l15;
      bias[ct] = (og < 32) ? bq[og] : bk[og - 32];
    }
    __syncthreads();

    floatx4 acc[4];
#pragma unroll
    for (int i = 0; i < 4; i++) acc[i] = (floatx4){0.f, 0.f, 0.f, 0.f};
#pragma unroll
    for (int ks = 0; ks < 8; ks++) {
      const int c0 = ks * 32;
      half8 a;
#pragma unroll
      for (int j = 0; j < 8; j++)
        a[j] = (_Float16)xb[(size_t)(c0 + q4 * 8 + j) * 4096 + n_row];
      const int ci = ks * 4 + q4;
#pragma unroll
      for (int ct = 0; ct < 4; ct++) {
        int og = ct * 16 + l15;
        half8 bf = *(const half8*)&sW[og * 256 + ((ci ^ (og & 7)) * 8)];
        acc[ct] = __builtin_amdgcn_mfma_f32_16x16x32_f16(a, bf, acc[ct], 0, 0, 0);
      }
    }
#pragma unroll
    for (int ct = 0; ct < 4; ct++) {
      int og = ct * 16 + l15;
#pragma unroll
      for (int r = 0; r < 4; r++) {
        int n = n0 + 16 * w + q4 * 4 + r;
        unsigned short hv = f32_to_f16u(acc[ct][r] + bias[ct]);
        if (og < 32) qT[((size_t)b * 4096 + n) * 32 + og] = hv;
        else         kT[((size_t)b * 4096 + n) * 32 + (og - 32)] = hv;
      }
    }
  } else {
    const float* xb = rgb + (size_t)b * 256 * 4096;
    float bias[16];
#pragma unroll
    for (int ct = 0; ct < 16; ct++) bias[ct] = bv[ct * 16 + l15];

    floatx4 acc[16];
#pragma unroll
    for (int ct = 0; ct < 16; ct++) acc[ct] = (floatx4){0.f, 0.f, 0.f, 0.f};

    // prefetch A-frag for ks=0
    half8 a_cur;
#pragma unroll
    for (int j = 0; j < 8; j++)
      a_cur[j] = (_Float16)xb[(size_t)(q4 * 8 + j) * 4096 + n_row];

    for (int ks = 0; ks < 8; ks++) {
      const int c0 = ks * 32;
      __syncthreads();  // prev B-frag reads done before overwrite
      // stage Wv slice [256 o][32 c] fp16, swizzled by (o&3)
#pragma unroll
      for (int u = 0; u < 4; u++) {
        int L = u * 256 + t;
        int o = L >> 2;
        int p = L & 3;
        int ci = p ^ (o & 3);
        const float* wr = Wv + (size_t)o * 256 + c0 + ci * 8;
        float4 w0 = *(const float4*)wr;
        float4 w1 = *(const float4*)(wr + 4);
        half8 h;
        h[0] = f32h(w0.x); h[1] = f32h(w0.y); h[2] = f32h(w0.z); h[3] = f32h(w0.w);
        h[4] = f32h(w1.x); h[5] = f32h(w1.y); h[6] = f32h(w1.z); h[7] = f32h(w1.w);
        *(half8*)&sW[(size_t)L * 8] = h;
      }
      __syncthreads();
      // prefetch next A-frag (overlaps the 16 MFMAs below)
      half8 a_nxt = a_cur;
      if (ks < 7) {
#pragma unroll
        for (int j = 0; j < 8; j++)
          a_nxt[j] = (_Float16)xb[(size_t)(c0 + 32 + q4 * 8 + j) * 4096 + n_row];
      }
#pragma unroll
      for (int ct = 0; ct < 16; ct++) {
        int o = ct * 16 + l15;
        half8 bf = *(const half8*)&sW[(o * 4 + (q4 ^ (o & 3))) * 8];
        acc[ct] = __builtin_amdgcn_mfma_f32_16x16x32_f16(a_cur, bf, acc[ct], 0, 0, 0);
      }
      a_cur = a_nxt;
    }

    // epilogue: 4 passes of 64 co, LDS transpose, coalesced stores
    unsigned short* tile = sW;  // [64][72]
#pragma unroll
    for (int pass = 0; pass < 4; pass++) {
      __syncthreads();
#pragma unroll
      for (int cc = 0; cc < 4; cc++) {
        int ct = pass * 4 + cc;
        int co_l = cc * 16 + l15;
#pragma unroll
        for (int r = 0; r < 4; r++) {
          int nl = 16 * w + q4 * 4 + r;
          tile[co_l * 72 + nl] = f32_to_f16u(acc[ct][r] + bias[ct]);
        }
      }
      __syncthreads();
#pragma unroll
      for (int it = 0; it < 2; it++) {
        int co_l = it * 32 + (t >> 3);
        int ch = t & 7;
        int4 val = *(const int4*)&tile[co_l * 72 + ch * 8];
        *(int4*)&v[((size_t)b * 256 + pass * 64 + co_l) * 4096 + n0 + ch * 8] = val;
      }
    }
  }
}

// ---------------------------------------------------------------------------
// Flash attention, split-m, co-split PV:
// block = (64 n, b, m-chunk 1024), 4 waves. Per 32-m iter:
//  - stage V [256co][32m] + K [32m][32c] (swizzled)
//  - each wave: S for its 16 n via 16x16x32 (2 MFMA), exp2, write P to
//    SHARED [64n][40] tile; barrier
//  - each wave: PV for its 64-co slice over ALL 64 n via 32x32x16
//    (8 MFMA, 4 P-frag + 4 V-frag ds_read_b128) -> V tile read once/block.
// ---------------------------------------------------------------------------
__global__ __launch_bounds__(256, 4) void attn_kernel(
    const unsigned short* __restrict__ qT,  // [b][n][32] fp16
    const unsigned short* __restrict__ kT,  // [b][m][32] fp16
    const unsigned short* __restrict__ v,   // [b][co][m] fp16
    unsigned short* __restrict__ Op,        // [chunk][b][co][n] fp16 unnormalized
    float* __restrict__ lW)                 // [chunk][b][n]
{
  __shared__ __align__(16) unsigned char smem[36864];
  unsigned short* sV = (unsigned short*)smem;              // [256co][32m] swizzled (16384 B)
  unsigned short* sK = (unsigned short*)(smem + 16384);    // [32m][32c] swizzled (2048 B)
  unsigned short* sP = (unsigned short*)(smem + 18432);    // [64n][pitch 40] (5120 B)

  const int n0 = blockIdx.x * 64;
  const int b  = blockIdx.y;
  const int chunk = blockIdx.z;
  const int t  = threadIdx.x;
  const int w  = t >> 6;
  const int lane = t & 63;
  const int l15 = lane & 15;
  const int q4  = lane >> 4;
  const int l31 = lane & 31;
  const int hi  = lane >> 5;

  const unsigned short* qrow = qT + ((size_t)b * 4096 + n0 + 16 * w + l15) * 32 + q4 * 8;
  half8 aq = *(const half8*)qrow;

  const unsigned short* vB = v  + (size_t)b * 256 * 4096;
  const unsigned short* kB = kT + (size_t)b * 4096 * 32;

  float lsum[4] = {0.f, 0.f, 0.f, 0.f};
  floatx16 acc[2][2];
#pragma unroll
  for (int nt = 0; nt < 2; nt++)
#pragma unroll
    for (int ct = 0; ct < 2; ct++)
#pragma unroll
      for (int i = 0; i < 16; i++) acc[nt][ct][i] = 0.f;
  const floatx4 zf = (floatx4){0.f, 0.f, 0.f, 0.f};

  const int mbase = chunk * 1024;
  for (int mi = 0; mi < 1024; mi += 32) {
    const int m0 = mbase + mi;
    __syncthreads();  // A: all PV reads of prev iter done
    // stage V [256 co][32 m]: phys chunk p holds logical p ^ ((co>>1)&3)
#pragma unroll
    for (int j = 0; j < 4; j++) {
      int lin = j * 256 + t;
      int c = lin >> 2;
      int p = lin & 3;
      int lc = p ^ ((c >> 1) & 3);
      uint4 val = *(const uint4*)&vB[(size_t)c * 4096 + m0 + lc * 8];
      *(uint4*)&sV[lin * 8] = val;
    }
    if (t < 128) {
      int m = t >> 2, p = t & 3, lc = p ^ ((m >> 1) & 3);
      uint4 val = *(const uint4*)&kB[(size_t)(m0 + m) * 32 + lc * 8];
      *(uint4*)&sK[t * 8] = val;
    }
    __syncthreads();  // B: tiles visible

    // S phase: wave w computes rows 16w..16w+15
    half8 bk0 = *(const half8*)&sK[l15 * 32 + ((q4 ^ ((l15 >> 1) & 3)) * 8)];
    half8 bk1 = *(const half8*)&sK[(16 + l15) * 32 + ((q4 ^ (((16 + l15) >> 1) & 3)) * 8)];
    floatx4 s0 = __builtin_amdgcn_mfma_f32_16x16x32_f16(aq, bk0, zf, 0, 0, 0);
    floatx4 s1 = __builtin_amdgcn_mfma_f32_16x16x32_f16(aq, bk1, zf, 0, 0, 0);

    float p0[4], p1[4];
#pragma unroll
    for (int r = 0; r < 4; r++) {
      p0[r] = exp2f(s0[r] * L2E);
      p1[r] = exp2f(s1[r] * L2E);
      lsum[r] += p0[r] + p1[r];
    }
#pragma unroll
    for (int r = 0; r < 4; r++) {
      int row = w * 16 + q4 * 4 + r;
      sP[row * 40 + l15]      = f32_to_f16u(p0[r]);
      sP[row * 40 + 16 + l15] = f32_to_f16u(p1[r]);
    }
    __syncthreads();  // C: P visible to all waves

    // PV phase: wave w covers co = w*64 .. w*64+63, all 64 n
#pragma unroll
    for (int kst = 0; kst < 2; kst++) {
      half8 bvv[2];
#pragma unroll
      for (int ct = 0; ct < 2; ct++) {
        int co = w * 64 + ct * 32 + l31;
        int lc = (kst * 2 + hi) ^ ((co >> 1) & 3);
        bvv[ct] = *(const half8*)&sV[(co * 4 + lc) * 8];
      }
#pragma unroll
      for (int nt = 0; nt < 2; nt++) {
        half8 ap = *(const half8*)&sP[(nt * 32 + l31) * 40 + kst * 16 + hi * 8];
#pragma unroll
        for (int ct = 0; ct < 2; ct++) {
          acc[nt][ct] = __builtin_amdgcn_mfma_f32_32x32x16_f16(ap, bvv[ct], acc[nt][ct], 0, 0, 0);
        }
      }
    }
  }

  // l reduction (S frags are 16x16: reduce over the 16 lanes of each row group)
#pragma unroll
  for (int off = 1; off < 16; off <<= 1) {
#pragma unroll
    for (int r = 0; r < 4; r++) lsum[r] += __shfl_xor(lsum[r], off);
  }
  if (l15 == 0) {
#pragma unroll
    for (int r = 0; r < 4; r++)
      lW[((size_t)chunk * 4 + b) * 4096 + n0 + 16 * w + q4 * 4 + r] = lsum[r];
  }

  // epilogue: single-pass LDS transpose [256 co][pitch 72] fp16 = 36864 B
  __syncthreads();
  unsigned short* sO = (unsigned short*)smem;
#pragma unroll
  for (int nt = 0; nt < 2; nt++) {
#pragma unroll
    for (int ct = 0; ct < 2; ct++) {
      int co_l = w * 64 + ct * 32 + l31;
#pragma unroll
      for (int g = 0; g < 4; g++) {
        int nl = nt * 32 + g * 8 + hi * 4;
        ushort4 pk;
        pk.x = f32_to_f16u(acc[nt][ct][g * 4 + 0]);
        pk.y = f32_to_f16u(acc[nt][ct][g * 4 + 1]);
        pk.z = f32_to_f16u(acc[nt][ct][g * 4 + 2]);
        pk.w = f32_to_f16u(acc[nt][ct][g * 4 + 3]);
        *(ushort4*)&sO[co_l * 72 + nl] = pk;
      }
    }
  }
  __syncthreads();
#pragma unroll
  for (int s = 0; s < 8; s++) {
    int co_l = s * 32 + (t >> 3);
    int ch = t & 7;
    int4 val = *(const int4*)&sO[co_l * 72 + ch * 8];
    *(int4*)&Op[(((size_t)chunk * 4 + b) * 256 + co_l) * 4096 + n0 + ch * 8] = val;
  }
}

// ---------------------------------------------------------------------------
// Combine: out[b][co][n] = sum_ch Op[ch][b][co][n] / sum_ch lW[ch][b][n]
// ---------------------------------------------------------------------------
__global__ __launch_bounds__(256) void combine_kernel(
    const unsigned short* __restrict__ Op,
    const float* __restrict__ lW,
    float* __restrict__ out)
{
  const int t = threadIdx.x;
  const int b = blockIdx.y;
  const size_t n8 = (size_t)blockIdx.x * 2048 + (size_t)t * 8;
  const int co0 = blockIdx.z * 8;

  float sum[8] = {0.f, 0.f, 0.f, 0.f, 0.f, 0.f, 0.f, 0.f};
#pragma unroll
  for (int ch = 0; ch < 4; ch++) {
    const float* lp = lW + ((size_t)ch * 4 + b) * 4096 + n8;
    float4 a0 = *(const float4*)lp;
    float4 a1 = *(const float4*)(lp + 4);
    sum[0] += a0.x; sum[1] += a0.y; sum[2] += a0.z; sum[3] += a0.w;
    sum[4] += a1.x; sum[5] += a1.y; sum[6] += a1.z; sum[7] += a1.w;
  }
  float rl[8];
#pragma unroll
  for (int i = 0; i < 8; i++) rl[i] = 1.0f / sum[i];

#pragma unroll
  for (int cc = 0; cc < 8; cc++) {
    int co = co0 + cc;
    float o[8] = {0.f, 0.f, 0.f, 0.f, 0.f, 0.f, 0.f, 0.f};
#pragma unroll
    for (int ch = 0; ch < 4; ch++) {
      half8 hv = *(const half8*)&Op[(((size_t)ch * 4 + b) * 256 + co) * 4096 + n8];
#pragma unroll
      for (int i = 0; i < 8; i++) o[i] += (float)hv[i];
    }
    float* op = out + ((size_t)b * 256 + co) * 4096 + n8;
    float4 r0, r1;
    r0.x = o[0] * rl[0]; r0.y = o[1] * rl[1]; r0.z = o[2] * rl[2]; r0.w = o[3] * rl[3];
    r1.x = o[4] * rl[4]; r1.y = o[5] * rl[5]; r1.z = o[6] * rl[6]; r1.w = o[7] * rl[7];
    *(float4*)op = r0;
    *(float4*)(op + 4) = r1;
  }
}

extern "C" void kernel_launch(void* const* d_in, const int* in_sizes, int n_in,
                              void* d_out, int out_size, void* d_ws, size_t ws_size,
                              hipStream_t stream) {
  const float* rgb   = (const float*)d_in[0];
  const float* depth = (const float*)d_in[1];
  const float* Wq    = (const float*)d_in[2];
  const float* bq    = (const float*)d_in[3];
  const float* Wk    = (const float*)d_in[4];
  const float* bk    = (const float*)d_in[5];
  const float* Wv    = (const float*)d_in[6];
  const float* bv    = (const float*)d_in[7];
  float* out = (float*)d_out;

  unsigned short* qT = (unsigned short*)d_ws;             // 1 MB
  unsigned short* kT = qT + (size_t)4 * 4096 * 32;        // 1 MB
  unsigned short* vW = kT + (size_t)4 * 4096 * 32;        // 8 MB
  unsigned short* Op = vW + (size_t)4 * 256 * 4096;       // 33.5 MB
  float* lW = (float*)(Op + (size_t)4 * 4 * 256 * 4096);  // 256 KB

  dim3 pg(64, 4, 2);
  proj_kernel<<<pg, 256, 0, stream>>>(rgb, depth, Wq, bq, Wk, bk, Wv, bv, qT, kT, vW);
  dim3 ag(64, 4, 4);
  attn_kernel<<<ag, 256, 0, stream>>>(qT, kT, vW, Op, lW);
  dim3 cg(2, 4, 32);
  combine_kernel<<<cg, 256, 0, stream>>>(Op, lW, out);
}